// Round 11
// baseline (304.626 us; speedup 1.0000x reference)
//
#include <hip/hip_runtime.h>
#include <hip/hip_bf16.h>
#include <cstdint>

#define NTOPK 64
#define A_TOT 340
#define MS 28

// d_out element offsets (f32)
#define OFF_SCORES 0
#define OFF_BOXES  128
#define OFF_LABELS 640
#define OFF_MASKS  768
#define OFF_KEEP   33555200ull

typedef __attribute__((ext_vector_type(8))) short bf16x8;
typedef __attribute__((ext_vector_type(4))) float f32x4;

__device__ __forceinline__ float sigmoidf_(float x) { return 1.f / (1.f + expf(-x)); }
__device__ __forceinline__ float bf2f(unsigned u) {
  return __uint_as_float(u << 16);
}
__device__ __forceinline__ unsigned short f2bf(float f) {
  __hip_bfloat16 h = __float2bfloat16(f);  // RNE
  return *(unsigned short*)&h;
}

// ---- Kernel P: fused prep. blocks 0-1: decode+NMS; 2-129: weight transpose;
// ---- 130-385: merged feature build (nearest-resize folded, f32->bf16).
__global__ __launch_bounds__(256) void k_prep(
    const float* __restrict__ p0, const float* __restrict__ p1,
    const float* __restrict__ p2, const float* __restrict__ p3,
    const float* __restrict__ f0, const float* __restrict__ f1,
    const float* __restrict__ f2, const float* __restrict__ f3,
    const float* __restrict__ w1,
    float* __restrict__ out,
    float* __restrict__ ws_boxes, int* __restrict__ ws_keep,
    int* __restrict__ ws_boxint,
    unsigned short* __restrict__ wt, unsigned short* __restrict__ mg)
{
  __shared__ __align__(16) char smem_raw[128 * 260 * 2];
  const int bid = blockIdx.x;
  const int t = threadIdx.x;

  if (bid < 2) {
    // ---------------- decode + stable top-64 + shfl NMS ----------------
    const int b = bid;
    float* sc = (float*)smem_raw;                    // [A_TOT]
    float(*bx)[4] = (float(*)[4])(sc + A_TOT);       // [A_TOT][4]
    float* tk_score = (float*)(bx + A_TOT);          // [64]
    float(*tk_box)[4] = (float(*)[4])(tk_score + 64);

    for (int a = t; a < A_TOT; a += 256) {
      const float* pp; int W, HW, la; float stride;
      if (a < 256)      { pp = p0; W = 16; HW = 256; la = a;       stride = 32.f;  }
      else if (a < 320) { pp = p1; W = 8;  HW = 64;  la = a - 256; stride = 64.f;  }
      else if (a < 336) { pp = p2; W = 4;  HW = 16;  la = a - 320; stride = 128.f; }
      else              { pp = p3; W = 2;  HW = 4;   la = a - 336; stride = 256.f; }
      const float* base = pp + (size_t)b * 6 * HW + la;
      float v0 = base[0], v1 = base[HW], v2 = base[2 * HW], v3 = base[3 * HW], v4 = base[4 * HW];
      int gx = la % W, gy = la / W;
      float cx = (v0 + (float)gx) * stride;
      float cy = (v1 + (float)gy) * stride;
      float w_ = expf(v2) * stride;
      float h_ = expf(v3) * stride;
      float score = sigmoidf_(v4);
      sc[a] = (score > 0.5f) ? score : 0.f;
      bx[a][0] = cx - 0.5f * w_;
      bx[a][1] = cy - 0.5f * h_;
      bx[a][2] = cx + 0.5f * w_;
      bx[a][3] = cy + 0.5f * h_;
    }
    __syncthreads();

    // stable top-k by rank counting (ties -> lower index, like lax.top_k)
    for (int a = t; a < A_TOT; a += 256) {
      float my = sc[a];
      int rank = 0;
      for (int j = 0; j < A_TOT; ++j) {
        float o = sc[j];
        rank += (o > my) || (o == my && j < a);
      }
      if (rank < NTOPK) {
        tk_score[rank] = my;
        tk_box[rank][0] = bx[a][0];
        tk_box[rank][1] = bx[a][1];
        tk_box[rank][2] = bx[a][2];
        tk_box[rank][3] = bx[a][3];
      }
    }
    __syncthreads();

    // wave-synchronous sequential NMS on wave 0
    if (t < NTOPK) {
      float x0 = tk_box[t][0], y0 = tk_box[t][1];
      float x1 = tk_box[t][2], y1 = tk_box[t][3];
      float s = tk_score[t];
      float area = fmaxf(x1 - x0, 0.f) * fmaxf(y1 - y0, 0.f);
      int keep = (s > 0.5f) ? 1 : 0;
      for (int i = 0; i < NTOPK - 1; ++i) {
        int   ki = __shfl(keep, i);
        float a0 = __shfl(x0, i);
        float c0 = __shfl(y0, i);
        float a1 = __shfl(x1, i);
        float c1 = __shfl(y1, i);
        float ai = __shfl(area, i);
        if (ki && t > i && keep) {
          float ix0 = fmaxf(a0, x0), iy0 = fmaxf(c0, y0);
          float ix1 = fminf(a1, x1), iy1 = fminf(c1, y1);
          float inter = fmaxf(ix1 - ix0, 0.f) * fmaxf(iy1 - iy0, 0.f);
          float uni = ai + area - inter;
          float iou = inter / fmaxf(uni, 1e-9f);
          if (iou > 0.5f) keep = 0;
        }
      }
      int box = b * NTOPK + t;
      out[OFF_SCORES + box] = keep ? s : 0.f;
      float bv[4] = {x0, y0, x1, y1};
      #pragma unroll
      for (int c = 0; c < 4; ++c) {
        out[OFF_BOXES + box * 4 + c] = bv[c];
        ws_boxes[box * 4 + c] = bv[c];
        float bc = fminf(fmaxf(bv[c], 0.f), 511.f);
        ws_boxint[box * 4 + c] = (int)bc;
      }
      out[OFF_LABELS + box] = 0.f;
      out[OFF_KEEP + box] = keep ? 1.f : 0.f;
      ws_keep[box] = keep;
    }
    return;
  }

  if (bid < 130) {
    // -- w1 f32 [co][ci][3][3] -> wt bf16 [cq][chunk][tap][co32][ci32] ------
    const int co = bid - 2;
    const int ci = t;            // 0..255
    const int c = ci >> 5, cil = ci & 31;
    const int cq = co >> 5, col = co & 31;
    const float* src = w1 + ((size_t)co * 256 + ci) * 9;
    #pragma unroll
    for (int tap = 0; tap < 9; ++tap)
      wt[(((size_t)(cq * 8 + c) * 9 + tap)) * 1024 + col * 32 + cil] = f2bf(src[tap]);
    return;
  }

  // -------- merged[b][y][x][c] bf16 build --------
  {
    const int idx = bid - 130;
    const int b = idx >> 7;
    const int y = idx & 127;
    unsigned short* tile = (unsigned short*)smem_raw;   // [128*260]
    const int x = t & 127, ch = t >> 7;

    {
      const float* src = f0 + ((size_t)b * 64) * 16384 + y * 128 + x;
      for (int cc = 0; cc < 32; ++cc) {
        int cl = ch * 32 + cc;
        tile[x * 260 + cl] = f2bf(src[(size_t)cl * 16384]);
      }
    }
    {
      const float* src = f1 + ((size_t)b * 64) * 4096 + (y >> 1) * 64 + (x >> 1);
      for (int cc = 0; cc < 32; ++cc) {
        int cl = ch * 32 + cc;
        tile[x * 260 + 64 + cl] = f2bf(src[(size_t)cl * 4096]);
      }
    }
    {
      const float* src = f2 + ((size_t)b * 64) * 1024 + (y >> 2) * 32 + (x >> 2);
      for (int cc = 0; cc < 32; ++cc) {
        int cl = ch * 32 + cc;
        tile[x * 260 + 128 + cl] = f2bf(src[(size_t)cl * 1024]);
      }
    }
    {
      const float* src = f3 + ((size_t)b * 64) * 256 + (y >> 3) * 16 + (x >> 3);
      for (int cc = 0; cc < 32; ++cc) {
        int cl = ch * 32 + cc;
        tile[x * 260 + 192 + cl] = f2bf(src[(size_t)cl * 256]);
      }
    }
    __syncthreads();
    unsigned short* dst = mg + (((size_t)b * 128 + y) * 128) * 256;
    for (int it = 0; it < 32; ++it) {
      int qq = t + it * 256;
      int xx = qq >> 6, cg = qq & 63;
      *(ushort4*)(dst + xx * 256 + cg * 4) = *(ushort4*)&tile[xx * 260 + cg * 4];
    }
  }
}

// ------- Kernel S: materialize ROI tiles, bilinear from merged --------------
// CHUNK-MAJOR layout: roi[box][c 0..7][r 0..29][cell 0..31][ci32] bf16.
// XCD swizzle: bid%8 == box%8 (same XCD as the consuming k_conv blocks).
__global__ __launch_bounds__(256) void k_roistage(
    const unsigned short* __restrict__ mg,
    const float* __restrict__ ws_boxes, const int* __restrict__ ws_keep,
    unsigned short* __restrict__ roi)
{
  const int boxLo = blockIdx.x & 7;
  const int r2 = blockIdx.x >> 3;
  const int r = r2 % 30;
  const int box = ((r2 / 30) << 3) | boxLo;
  if (!ws_keep[box]) return;
  const int t = threadIdx.x;
  unsigned short* rbox = roi + (size_t)box * 8 * 30 * 1024;
  const int gr = r - 1;

  if (gr < 0 || gr > 27) {
    uint4 z = {0u, 0u, 0u, 0u};
    for (int e = t; e < 1024; e += 256) {
      int chunk = e >> 7, rem = e & 127;
      size_t off = ((size_t)(chunk * 30 + r)) * 1024 + rem * 8;
      *(uint4*)(rbox + off) = z;
    }
    return;
  }

  __shared__ int   xa_s[MS], xb_s[MS];
  __shared__ float fx_s[MS];
  __shared__ float by_s[4];
  if (t < 4) by_s[t] = ws_boxes[box * 4 + t];
  __syncthreads();
  const float b0 = by_s[0] * 0.25f, b1_ = by_s[1] * 0.25f;
  const float b2_ = by_s[2] * 0.25f, b3_ = by_s[3] * 0.25f;
  if (t < MS) {
    float bw = (b2_ - b0) * (1.f / MS);
    float x = b0 + ((float)t + 0.5f) * bw;
    x = fminf(fmaxf(x, 0.f), 127.f);
    int x0 = (int)floorf(x);
    xa_s[t] = x0; xb_s[t] = min(x0 + 1, 127); fx_s[t] = x - (float)x0;
  }
  float bh = (b3_ - b1_) * (1.f / MS);
  float yy = b1_ + ((float)gr + 0.5f) * bh;
  yy = fminf(fmaxf(yy, 0.f), 127.f);
  int ya = (int)floorf(yy);
  int yb = min(ya + 1, 127);
  float fy = yy - (float)ya;
  __syncthreads();

  const int b = box >> 6;
  const unsigned short* mgb = mg + ((size_t)b * 128 * 128) * 256;

  // e -> chunk = e>>7, cell = (e&127)>>2, quad = e&3; U (ci octet) = chunk*4+quad
  for (int e = t; e < 1024; e += 256) {
    int chunk = e >> 7, rem = e & 127;
    int cell = rem >> 2, quad = rem & 3;
    size_t off = ((size_t)(chunk * 30 + r)) * 1024 + rem * 8;
    int gc = cell - 1;
    if (gc < 0 || gc > 27) {
      uint4 z = {0u, 0u, 0u, 0u};
      *(uint4*)(rbox + off) = z;
      continue;
    }
    int U = chunk * 4 + quad;
    int xa = xa_s[gc], xb = xb_s[gc];
    float fx = fx_s[gc];
    float w00 = (1.f - fy) * (1.f - fx), w01 = (1.f - fy) * fx;
    float w10 = fy * (1.f - fx),         w11 = fy * fx;
    uint4 A = *(const uint4*)(mgb + ((size_t)(ya * 128 + xa)) * 256 + U * 8);
    uint4 B = *(const uint4*)(mgb + ((size_t)(ya * 128 + xb)) * 256 + U * 8);
    uint4 C = *(const uint4*)(mgb + ((size_t)(yb * 128 + xa)) * 256 + U * 8);
    uint4 D = *(const uint4*)(mgb + ((size_t)(yb * 128 + xb)) * 256 + U * 8);
    const unsigned* pa = (const unsigned*)&A;
    const unsigned* pb = (const unsigned*)&B;
    const unsigned* pc = (const unsigned*)&C;
    const unsigned* pd = (const unsigned*)&D;
    unsigned o[4];
    #pragma unroll
    for (int k2 = 0; k2 < 4; ++k2) {
      float lo = bf2f(pa[k2] & 0xffffu) * w00 + bf2f(pb[k2] & 0xffffu) * w01 +
                 bf2f(pc[k2] & 0xffffu) * w10 + bf2f(pd[k2] & 0xffffu) * w11;
      float hi = bf2f(pa[k2] >> 16) * w00 + bf2f(pb[k2] >> 16) * w01 +
                 bf2f(pc[k2] >> 16) * w10 + bf2f(pd[k2] >> 16) * w11;
      o[k2] = (unsigned)f2bf(lo) | ((unsigned)f2bf(hi) << 16);
    }
    uint4 pk; pk.x = o[0]; pk.y = o[1]; pk.z = o[2]; pk.w = o[3];
    *(uint4*)(rbox + off) = pk;
  }
}

// ------- Kernel G: conv1 3x3 as 9 shifted MFMA GEMMs + SiLU + conv2 --------
// grid (box, quarter, co-quad) = 2048, XCD swizzle bid%8 == box%8.
// A held in VGPRs (loaded coalesced once per chunk); B double-buffered in LDS
// (un-swizzled; reads are bank-even), register-prefetched: per chunk =
// [loadA][1 barrier][prefB(c+1)][compute][storeB(c+1) into other buffer].
__global__ __launch_bounds__(256, 3) void k_conv(
    const unsigned short* __restrict__ roi,  // [box][c][r30][cell32][ci32]
    const unsigned short* __restrict__ wt,   // [cq][c][tap][co32][ci32]
    const float* __restrict__ b1, const float* __restrict__ w2,
    const int* __restrict__ ws_keep,
    float* __restrict__ ws_logit4)           // [128][4][784]
{
  const int bid = blockIdx.x;
  const int boxLo = bid & 7;
  const int r1 = bid >> 3;
  const int cq = r1 & 3;
  const int q = (r1 >> 2) & 3;
  const int box = ((r1 >> 4) << 3) | boxLo;
  if (!ws_keep[box]) return;
  const int t = threadIdx.x;
  const int lane = t & 63, wv = t >> 6;
  const int laneN = lane & 15, kg = lane >> 4;

  __shared__ __align__(16) unsigned short ldsB[2][9216];  // [buf][r9][cell32][ci32]

  // per-(i,dx) B addresses (linear); act[i]: tile contains real pixels
  int badd[4][3];
  bool act[4];
  #pragma unroll
  for (int i = 0; i < 4; ++i) {
    int tile = wv * 4 + i;
    act[i] = (tile * 16) < 196;
    int p = tile * 16 + laneN;
    if (p > 195) p = 195;
    int py = p / 28, px = p - py * 28;
    #pragma unroll
    for (int dx = 0; dx < 3; ++dx)
      badd[i][dx] = (py * 32 + px + dx) * 32 + kg * 8;
  }

  f32x4 acc[2][4];
  #pragma unroll
  for (int m = 0; m < 2; ++m)
    #pragma unroll
    for (int i = 0; i < 4; ++i) acc[m][i] = (f32x4){0.f, 0.f, 0.f, 0.f};

  const uint4* rbase = (const uint4*)roi;
  const bf16x8* wtl = (const bf16x8*)wt;

  uint4 gb0, gb1, gb2, gb3, gb4;   // B staging regs (1152 uint4 / block)
  auto prefB = [&](int c) {
    const uint4* s = rbase + ((size_t)(box * 8 + c) * 30 + q * 7) * 128;
    gb0 = s[t]; gb1 = s[t + 256]; gb2 = s[t + 512]; gb3 = s[t + 768];
    if (t < 128) gb4 = s[t + 1024];
  };
  auto storeB = [&](int buf) {
    uint4* d = (uint4*)ldsB[buf];
    d[t] = gb0; d[t + 256] = gb1; d[t + 512] = gb2; d[t + 768] = gb3;
    if (t < 128) d[t + 1024] = gb4;
  };

  prefB(0);
  storeB(0);
  #pragma unroll 1
  for (int c = 0; c < 8; ++c) {
    // A(c) -> VGPRs: 18 coalesced b128 loads (wave-identical -> L1)
    bf16x8 A0[9], A1[9];
    {
      const bf16x8* wa = wtl + (size_t)(cq * 8 + c) * 1152;
      #pragma unroll
      for (int tap = 0; tap < 9; ++tap) {
        A0[tap] = wa[tap * 128 + laneN * 4 + kg];
        A1[tap] = wa[tap * 128 + 64 + laneN * 4 + kg];
      }
    }
    __syncthreads();                 // buf(c) stores + A loads drained
    if (c < 7) prefB(c + 1);         // flies during compute
    const unsigned short* rb = ldsB[c & 1];
    #pragma unroll
    for (int tap = 0; tap < 9; ++tap) {
      const int dy = tap / 3, dx = tap % 3;
      #pragma unroll
      for (int i = 0; i < 4; ++i) {
        if (act[i]) {
          bf16x8 bv = *(const bf16x8*)(rb + badd[i][dx] + dy * 1024);
          acc[0][i] = __builtin_amdgcn_mfma_f32_16x16x32_bf16(A0[tap], bv, acc[0][i], 0, 0, 0);
          acc[1][i] = __builtin_amdgcn_mfma_f32_16x16x32_bf16(A1[tap], bv, acc[1][i], 0, 0, 0);
        }
      }
    }
    if (c < 7) storeB((c + 1) & 1);  // other buffer: no barrier needed here
  }

  // epilogue: +b1, SiLU, dot w2 over this block's 32 co, reduce kg via shfl
  float b1v[2][4], w2v[2][4];
  #pragma unroll
  for (int m = 0; m < 2; ++m)
    #pragma unroll
    for (int r = 0; r < 4; ++r) {
      int co = cq * 32 + m * 16 + kg * 4 + r;
      b1v[m][r] = b1[co];
      w2v[m][r] = w2[co];
    }
  #pragma unroll
  for (int i = 0; i < 4; ++i) {
    if (!act[i]) continue;
    float part = 0.f;
    #pragma unroll
    for (int m = 0; m < 2; ++m)
      #pragma unroll
      for (int r = 0; r < 4; ++r) {
        float h = acc[m][i][r] + b1v[m][r];
        part = fmaf(w2v[m][r], h * sigmoidf_(h), part);
      }
    part += __shfl_xor(part, 16);
    part += __shfl_xor(part, 32);
    int p = (wv * 4 + i) * 16 + laneN;
    if (kg == 0 && p < 196)
      ws_logit4[((size_t)box * 4 + cq) * 784 + q * 196 + p] = part;
  }
}

// ---------------- Kernel D: sigmoid + paste + binarize (f32 out) ------------
// grid: box(128) x row-group(16 x 32 rows) = 2048 blocks.
__global__ __launch_bounds__(256) void k_paste(
    const float* __restrict__ ws_logit4, const int* __restrict__ ws_keep,
    const int* __restrict__ ws_boxint, const float* __restrict__ b2,
    float* __restrict__ out)
{
  const int box = blockIdx.x >> 4;
  const int yo  = blockIdx.x & 15;
  const int t = threadIdx.x;
  float* mb = out + OFF_MASKS + (size_t)box * 262144 + (size_t)yo * 32 * 512;

  if (!ws_keep[box]) {
    f32x4 z = {0.f, 0.f, 0.f, 0.f};
    f32x4* p = (f32x4*)mb;
    for (int e = t; e < 4096; e += 256)
      __builtin_nontemporal_store(z, p + e);
    return;
  }

  __shared__ float soft[784];
  __shared__ int iys[32];
  __shared__ int bi[4];
  if (t < 4) bi[t] = ws_boxint[box * 4 + t];
  __syncthreads();
  const int x0 = bi[0], y0 = bi[1], x1 = bi[2], y1 = bi[3];
  const int w = x1 - x0 + 1, h = y1 - y0 + 1;
  const float b2v = b2[0];
  const float* l0 = ws_logit4 + (size_t)box * 4 * 784;

  for (int e = t; e < 784; e += 256)
    soft[e] = sigmoidf_(l0[e] + l0[784 + e] + l0[1568 + e] + l0[2352 + e] + b2v);
  if (t < 32) {
    int Y = yo * 32 + t;
    int vy = (Y - y0) * MS;
    int iy = (vy >= 0) ? (vy / h) : 0;
    iys[t] = min(max(iy, 0), MS - 1);
  }
  __syncthreads();

  const int c4 = (t & 127) * 4;   // 4 columns per thread
  const int rr = t >> 7;          // row interleave 0/1
  int ixr[4];
  bool inx[4];
  #pragma unroll
  for (int u = 0; u < 4; ++u) {
    int X = c4 + u;
    int vx = (X - x0) * MS;
    int ix = (vx >= 0) ? (vx / w) : 0;
    ixr[u] = min(max(ix, 0), MS - 1);
    inx[u] = (X >= x0) && (X <= x1);
  }

  int prev_iy = -1;
  f32x4 v = {0.f, 0.f, 0.f, 0.f};
  #pragma unroll 1
  for (int it = 0; it < 16; ++it) {
    int Yl = it * 2 + rr;
    int Y = yo * 32 + Yl;
    f32x4 o;
    if (Y >= y0 && Y <= y1) {
      int iy = iys[Yl];
      if (iy != prev_iy) {
        prev_iy = iy;
        #pragma unroll
        for (int u = 0; u < 4; ++u)
          v[u] = (inx[u] && soft[iy * MS + ixr[u]] > 0.5f) ? 1.f : 0.f;
      }
      o = v;
    } else {
      o = (f32x4){0.f, 0.f, 0.f, 0.f};
    }
    __builtin_nontemporal_store(o, (f32x4*)(mb + (size_t)Yl * 512 + c4));
  }
}

extern "C" void kernel_launch(void* const* d_in, const int* in_sizes, int n_in,
                              void* d_out, int out_size, void* d_ws, size_t ws_size,
                              hipStream_t stream) {
  const float* p0 = (const float*)d_in[0];
  const float* p1 = (const float*)d_in[1];
  const float* p2 = (const float*)d_in[2];
  const float* p3 = (const float*)d_in[3];
  const float* f0 = (const float*)d_in[4];
  const float* f1 = (const float*)d_in[5];
  const float* f2 = (const float*)d_in[6];
  const float* f3 = (const float*)d_in[7];
  const float* w1 = (const float*)d_in[8];
  const float* b1 = (const float*)d_in[9];
  const float* w2 = (const float*)d_in[10];
  const float* b2 = (const float*)d_in[11];
  float* out = (float*)d_out;

  float* wsf = (float*)d_ws;
  float*          ws_boxes  = wsf;                               // 512 f32
  int*            ws_keep   = (int*)(wsf + 512);                 // 128
  int*            ws_boxint = (int*)(wsf + 640);                 // 512
  float*          ws_logit4 = wsf + 1152;                        // 128*4*784 f32
  unsigned short* ws_wt     = (unsigned short*)(wsf + 402560);   // 4*8*9*1024 bf16
  unsigned short* ws_merged = (unsigned short*)(wsf + 550016);   // 2*128*128*256 bf16
  unsigned short* ws_roi    = (unsigned short*)(wsf + 4744320);  // 128*8*30*1024 bf16
  // total ws use: 20,472,960 f32 = 81.9 MB

  k_prep<<<386, 256, 0, stream>>>(p0, p1, p2, p3, f0, f1, f2, f3, w1,
                                  out, ws_boxes, ws_keep, ws_boxint,
                                  ws_wt, ws_merged);
  k_roistage<<<3840, 256, 0, stream>>>(ws_merged, ws_boxes, ws_keep, ws_roi);
  k_conv<<<2048, 256, 0, stream>>>(ws_roi, ws_wt, b1, w2, ws_keep, ws_logit4);
  k_paste<<<2048, 256, 0, stream>>>(ws_logit4, ws_keep, ws_boxint, b2, out);
}

// Round 12
// 281.847 us; speedup vs baseline: 1.0808x; 1.0808x over previous
//
#include <hip/hip_runtime.h>
#include <hip/hip_bf16.h>
#include <cstdint>

#define NTOPK 64
#define A_TOT 340
#define MS 28

// d_out element offsets (f32)
#define OFF_SCORES 0
#define OFF_BOXES  128
#define OFF_LABELS 640
#define OFF_MASKS  768
#define OFF_KEEP   33555200ull

typedef __attribute__((ext_vector_type(8))) short bf16x8;
typedef __attribute__((ext_vector_type(4))) float f32x4;

__device__ __forceinline__ float sigmoidf_(float x) { return 1.f / (1.f + expf(-x)); }
__device__ __forceinline__ float bf2f(unsigned u) {
  return __uint_as_float(u << 16);
}
__device__ __forceinline__ unsigned short f2bf(float f) {
  __hip_bfloat16 h = __float2bfloat16(f);  // RNE
  return *(unsigned short*)&h;
}

// ---- Kernel P: fused prep. blocks 0-1: decode+NMS; 2-129: weight transpose;
// ---- 130-385: merged feature build (nearest-resize folded, f32->bf16).
__global__ __launch_bounds__(256) void k_prep(
    const float* __restrict__ p0, const float* __restrict__ p1,
    const float* __restrict__ p2, const float* __restrict__ p3,
    const float* __restrict__ f0, const float* __restrict__ f1,
    const float* __restrict__ f2, const float* __restrict__ f3,
    const float* __restrict__ w1,
    float* __restrict__ out,
    float* __restrict__ ws_boxes, int* __restrict__ ws_keep,
    int* __restrict__ ws_boxint,
    unsigned short* __restrict__ wt, unsigned short* __restrict__ mg)
{
  __shared__ __align__(16) char smem_raw[128 * 260 * 2];
  const int bid = blockIdx.x;
  const int t = threadIdx.x;

  if (bid < 2) {
    // ---------------- decode + stable top-64 + shfl NMS ----------------
    const int b = bid;
    float* sc = (float*)smem_raw;                    // [A_TOT]
    float(*bx)[4] = (float(*)[4])(sc + A_TOT);       // [A_TOT][4]
    float* tk_score = (float*)(bx + A_TOT);          // [64]
    float(*tk_box)[4] = (float(*)[4])(tk_score + 64);

    for (int a = t; a < A_TOT; a += 256) {
      const float* pp; int W, HW, la; float stride;
      if (a < 256)      { pp = p0; W = 16; HW = 256; la = a;       stride = 32.f;  }
      else if (a < 320) { pp = p1; W = 8;  HW = 64;  la = a - 256; stride = 64.f;  }
      else if (a < 336) { pp = p2; W = 4;  HW = 16;  la = a - 320; stride = 128.f; }
      else              { pp = p3; W = 2;  HW = 4;   la = a - 336; stride = 256.f; }
      const float* base = pp + (size_t)b * 6 * HW + la;
      float v0 = base[0], v1 = base[HW], v2 = base[2 * HW], v3 = base[3 * HW], v4 = base[4 * HW];
      int gx = la % W, gy = la / W;
      float cx = (v0 + (float)gx) * stride;
      float cy = (v1 + (float)gy) * stride;
      float w_ = expf(v2) * stride;
      float h_ = expf(v3) * stride;
      float score = sigmoidf_(v4);
      sc[a] = (score > 0.5f) ? score : 0.f;
      bx[a][0] = cx - 0.5f * w_;
      bx[a][1] = cy - 0.5f * h_;
      bx[a][2] = cx + 0.5f * w_;
      bx[a][3] = cy + 0.5f * h_;
    }
    __syncthreads();

    // stable top-k by rank counting (ties -> lower index, like lax.top_k)
    for (int a = t; a < A_TOT; a += 256) {
      float my = sc[a];
      int rank = 0;
      for (int j = 0; j < A_TOT; ++j) {
        float o = sc[j];
        rank += (o > my) || (o == my && j < a);
      }
      if (rank < NTOPK) {
        tk_score[rank] = my;
        tk_box[rank][0] = bx[a][0];
        tk_box[rank][1] = bx[a][1];
        tk_box[rank][2] = bx[a][2];
        tk_box[rank][3] = bx[a][3];
      }
    }
    __syncthreads();

    // wave-synchronous sequential NMS on wave 0
    if (t < NTOPK) {
      float x0 = tk_box[t][0], y0 = tk_box[t][1];
      float x1 = tk_box[t][2], y1 = tk_box[t][3];
      float s = tk_score[t];
      float area = fmaxf(x1 - x0, 0.f) * fmaxf(y1 - y0, 0.f);
      int keep = (s > 0.5f) ? 1 : 0;
      for (int i = 0; i < NTOPK - 1; ++i) {
        int   ki = __shfl(keep, i);
        float a0 = __shfl(x0, i);
        float c0 = __shfl(y0, i);
        float a1 = __shfl(x1, i);
        float c1 = __shfl(y1, i);
        float ai = __shfl(area, i);
        if (ki && t > i && keep) {
          float ix0 = fmaxf(a0, x0), iy0 = fmaxf(c0, y0);
          float ix1 = fminf(a1, x1), iy1 = fminf(c1, y1);
          float inter = fmaxf(ix1 - ix0, 0.f) * fmaxf(iy1 - iy0, 0.f);
          float uni = ai + area - inter;
          float iou = inter / fmaxf(uni, 1e-9f);
          if (iou > 0.5f) keep = 0;
        }
      }
      int box = b * NTOPK + t;
      out[OFF_SCORES + box] = keep ? s : 0.f;
      float bv[4] = {x0, y0, x1, y1};
      #pragma unroll
      for (int c = 0; c < 4; ++c) {
        out[OFF_BOXES + box * 4 + c] = bv[c];
        ws_boxes[box * 4 + c] = bv[c];
        float bc = fminf(fmaxf(bv[c], 0.f), 511.f);
        ws_boxint[box * 4 + c] = (int)bc;
      }
      out[OFF_LABELS + box] = 0.f;
      out[OFF_KEEP + box] = keep ? 1.f : 0.f;
      ws_keep[box] = keep;
    }
    return;
  }

  if (bid < 130) {
    // -- w1 f32 [co][ci][3][3] -> wt bf16 [cq][chunk][tap][co32][ci32] with
    // -- the ci-octet swizzle BAKED IN: octet slot = (cil>>3) ^ ((col>>1)&3).
    const int co = bid - 2;
    const int ci = t;            // 0..255
    const int c = ci >> 5, cil = ci & 31;
    const int cq = co >> 5, col = co & 31;
    const int slot = ((cil >> 3) ^ ((col >> 1) & 3)) * 8 + (cil & 7);
    const float* src = w1 + ((size_t)co * 256 + ci) * 9;
    #pragma unroll
    for (int tap = 0; tap < 9; ++tap)
      wt[(((size_t)(cq * 8 + c) * 9 + tap)) * 1024 + col * 32 + slot] = f2bf(src[tap]);
    return;
  }

  // -------- merged[b][y][x][c] bf16 build --------
  {
    const int idx = bid - 130;
    const int b = idx >> 7;
    const int y = idx & 127;
    unsigned short* tile = (unsigned short*)smem_raw;   // [128*260]
    const int x = t & 127, ch = t >> 7;

    {
      const float* src = f0 + ((size_t)b * 64) * 16384 + y * 128 + x;
      for (int cc = 0; cc < 32; ++cc) {
        int cl = ch * 32 + cc;
        tile[x * 260 + cl] = f2bf(src[(size_t)cl * 16384]);
      }
    }
    {
      const float* src = f1 + ((size_t)b * 64) * 4096 + (y >> 1) * 64 + (x >> 1);
      for (int cc = 0; cc < 32; ++cc) {
        int cl = ch * 32 + cc;
        tile[x * 260 + 64 + cl] = f2bf(src[(size_t)cl * 4096]);
      }
    }
    {
      const float* src = f2 + ((size_t)b * 64) * 1024 + (y >> 2) * 32 + (x >> 2);
      for (int cc = 0; cc < 32; ++cc) {
        int cl = ch * 32 + cc;
        tile[x * 260 + 128 + cl] = f2bf(src[(size_t)cl * 1024]);
      }
    }
    {
      const float* src = f3 + ((size_t)b * 64) * 256 + (y >> 3) * 16 + (x >> 3);
      for (int cc = 0; cc < 32; ++cc) {
        int cl = ch * 32 + cc;
        tile[x * 260 + 192 + cl] = f2bf(src[(size_t)cl * 256]);
      }
    }
    __syncthreads();
    unsigned short* dst = mg + (((size_t)b * 128 + y) * 128) * 256;
    for (int it = 0; it < 32; ++it) {
      int qq = t + it * 256;
      int xx = qq >> 6, cg = qq & 63;
      *(ushort4*)(dst + xx * 256 + cg * 4) = *(ushort4*)&tile[xx * 260 + cg * 4];
    }
  }
}

// ------- Kernel S: materialize ROI tiles, bilinear from merged --------------
// CHUNK-MAJOR layout: roi[box][c 0..7][r 0..29][cell 0..31][ci32] bf16.
// XCD swizzle: bid%8 == box%8 (same XCD as the consuming k_conv blocks).
__global__ __launch_bounds__(256) void k_roistage(
    const unsigned short* __restrict__ mg,
    const float* __restrict__ ws_boxes, const int* __restrict__ ws_keep,
    unsigned short* __restrict__ roi)
{
  const int boxLo = blockIdx.x & 7;
  const int r2 = blockIdx.x >> 3;
  const int r = r2 % 30;
  const int box = ((r2 / 30) << 3) | boxLo;
  if (!ws_keep[box]) return;
  const int t = threadIdx.x;
  unsigned short* rbox = roi + (size_t)box * 8 * 30 * 1024;
  const int gr = r - 1;

  if (gr < 0 || gr > 27) {
    uint4 z = {0u, 0u, 0u, 0u};
    for (int e = t; e < 1024; e += 256) {
      int chunk = e >> 7, rem = e & 127;
      size_t off = ((size_t)(chunk * 30 + r)) * 1024 + rem * 8;
      *(uint4*)(rbox + off) = z;
    }
    return;
  }

  __shared__ int   xa_s[MS], xb_s[MS];
  __shared__ float fx_s[MS];
  __shared__ float by_s[4];
  if (t < 4) by_s[t] = ws_boxes[box * 4 + t];
  __syncthreads();
  const float b0 = by_s[0] * 0.25f, b1_ = by_s[1] * 0.25f;
  const float b2_ = by_s[2] * 0.25f, b3_ = by_s[3] * 0.25f;
  if (t < MS) {
    float bw = (b2_ - b0) * (1.f / MS);
    float x = b0 + ((float)t + 0.5f) * bw;
    x = fminf(fmaxf(x, 0.f), 127.f);
    int x0 = (int)floorf(x);
    xa_s[t] = x0; xb_s[t] = min(x0 + 1, 127); fx_s[t] = x - (float)x0;
  }
  float bh = (b3_ - b1_) * (1.f / MS);
  float yy = b1_ + ((float)gr + 0.5f) * bh;
  yy = fminf(fmaxf(yy, 0.f), 127.f);
  int ya = (int)floorf(yy);
  int yb = min(ya + 1, 127);
  float fy = yy - (float)ya;
  __syncthreads();

  const int b = box >> 6;
  const unsigned short* mgb = mg + ((size_t)b * 128 * 128) * 256;

  // e -> chunk = e>>7, cell = (e&127)>>2, quad = e&3; U (ci octet) = chunk*4+quad
  for (int e = t; e < 1024; e += 256) {
    int chunk = e >> 7, rem = e & 127;
    int cell = rem >> 2, quad = rem & 3;
    size_t off = ((size_t)(chunk * 30 + r)) * 1024 + rem * 8;
    int gc = cell - 1;
    if (gc < 0 || gc > 27) {
      uint4 z = {0u, 0u, 0u, 0u};
      *(uint4*)(rbox + off) = z;
      continue;
    }
    int U = chunk * 4 + quad;
    int xa = xa_s[gc], xb = xb_s[gc];
    float fx = fx_s[gc];
    float w00 = (1.f - fy) * (1.f - fx), w01 = (1.f - fy) * fx;
    float w10 = fy * (1.f - fx),         w11 = fy * fx;
    uint4 A = *(const uint4*)(mgb + ((size_t)(ya * 128 + xa)) * 256 + U * 8);
    uint4 B = *(const uint4*)(mgb + ((size_t)(ya * 128 + xb)) * 256 + U * 8);
    uint4 C = *(const uint4*)(mgb + ((size_t)(yb * 128 + xa)) * 256 + U * 8);
    uint4 D = *(const uint4*)(mgb + ((size_t)(yb * 128 + xb)) * 256 + U * 8);
    const unsigned* pa = (const unsigned*)&A;
    const unsigned* pb = (const unsigned*)&B;
    const unsigned* pc = (const unsigned*)&C;
    const unsigned* pd = (const unsigned*)&D;
    unsigned o[4];
    #pragma unroll
    for (int k2 = 0; k2 < 4; ++k2) {
      float lo = bf2f(pa[k2] & 0xffffu) * w00 + bf2f(pb[k2] & 0xffffu) * w01 +
                 bf2f(pc[k2] & 0xffffu) * w10 + bf2f(pd[k2] & 0xffffu) * w11;
      float hi = bf2f(pa[k2] >> 16) * w00 + bf2f(pb[k2] >> 16) * w01 +
                 bf2f(pc[k2] >> 16) * w10 + bf2f(pd[k2] >> 16) * w11;
      o[k2] = (unsigned)f2bf(lo) | ((unsigned)f2bf(hi) << 16);
    }
    uint4 pk; pk.x = o[0]; pk.y = o[1]; pk.z = o[2]; pk.w = o[3];
    *(uint4*)(rbox + off) = pk;
  }
}

// ------- Kernel G: conv1 3x3 as 9 shifted MFMA GEMMs + SiLU + conv2 --------
// grid (box, quarter, co-quad) = 2048, XCD swizzle bid%8 == box%8.
// Block: 196 px x 32 co; 4 waves x 4 n-tiles, m=2 per wave.
// A AND B staged in LDS per chunk (register-prefetched, single buffer,
// 2 barriers/chunk). BOTH A and B LDS reads are octet-swizzled -> <=2-way
// (free) bank aliasing. A swizzle is baked into the global wt layout.
__global__ __launch_bounds__(256, 4) void k_conv(
    const unsigned short* __restrict__ roi,  // [box][c][r30][cell32][ci32]
    const unsigned short* __restrict__ wt,   // [cq][c][tap][co32][ci32^swz]
    const float* __restrict__ b1, const float* __restrict__ w2,
    const int* __restrict__ ws_keep,
    float* __restrict__ ws_logit4)           // [128][4][784]
{
  const int bid = blockIdx.x;
  const int boxLo = bid & 7;
  const int r1 = bid >> 3;
  const int cq = r1 & 3;
  const int q = (r1 >> 2) & 3;
  const int box = ((r1 >> 4) << 3) | boxLo;
  if (!ws_keep[box]) return;
  const int t = threadIdx.x;
  const int lane = t & 63, wv = t >> 6;
  const int laneN = lane & 15, kg = lane >> 4;

  __shared__ __align__(16) unsigned short ldsA[9216];  // [tap][co32][ci32^swz]
  __shared__ __align__(16) unsigned short ldsB[9216];  // [r9][cell32][ci32^swz]

  // per-(i,dx) swizzled B addresses; act[i]: tile contains real pixels
  int badd[4][3];
  bool act[4];
  #pragma unroll
  for (int i = 0; i < 4; ++i) {
    int tile = wv * 4 + i;
    act[i] = (tile * 16) < 196;
    int p = tile * 16 + laneN;
    if (p > 195) p = 195;
    int py = p / 28, px = p - py * 28;
    #pragma unroll
    for (int dx = 0; dx < 3; ++dx) {
      int cell = px + dx;
      badd[i][dx] = (py * 32 + cell) * 32 + (kg ^ ((cell >> 1) & 3)) * 8;
    }
  }
  // swizzled A offsets (co = laneN and laneN+16 share the same xor term)
  const int aswz = (kg ^ ((laneN >> 1) & 3)) * 8;

  f32x4 acc[2][4];
  #pragma unroll
  for (int m = 0; m < 2; ++m)
    #pragma unroll
    for (int i = 0; i < 4; ++i) acc[m][i] = (f32x4){0.f, 0.f, 0.f, 0.f};

  const uint4* rbase = (const uint4*)roi;
  const uint4* wbase = (const uint4*)wt;

  uint4 ga0, ga1, ga2, ga3, ga4;   // A staging regs (1152 uint4 / block)
  uint4 gb0, gb1, gb2, gb3, gb4;   // B staging regs
  auto issue_load = [&](int c) {
    const uint4* wa = wbase + (size_t)(cq * 8 + c) * 1152;
    ga0 = wa[t]; ga1 = wa[t + 256]; ga2 = wa[t + 512]; ga3 = wa[t + 768];
    if (t < 128) ga4 = wa[t + 1024];
    const uint4* s = rbase + ((size_t)(box * 8 + c) * 30 + q * 7) * 128;
    gb0 = s[t]; gb1 = s[t + 256]; gb2 = s[t + 512]; gb3 = s[t + 768];
    if (t < 128) gb4 = s[t + 1024];
  };

  issue_load(0);
  #pragma unroll 1
  for (int c = 0; c < 8; ++c) {
    {
      // A: linear copy (swizzle baked into source layout)
      uint4* da = (uint4*)ldsA;
      da[t] = ga0; da[t + 256] = ga1; da[t + 512] = ga2; da[t + 768] = ga3;
      if (t < 128) da[t + 1024] = ga4;
      // B: swizzled on store
      auto put = [&](int e, uint4 v) {
        int r = e >> 7, rem = e & 127;
        int cell = rem >> 2, qd = rem & 3;
        *(uint4*)(ldsB + (r * 128 + cell * 4 + (qd ^ ((cell >> 1) & 3))) * 8) = v;
      };
      put(t, gb0); put(t + 256, gb1); put(t + 512, gb2); put(t + 768, gb3);
      if (t < 128) put(t + 1024, gb4);
    }
    __syncthreads();
    if (c < 7) issue_load(c + 1);   // in flight across compute
    #pragma unroll
    for (int tap = 0; tap < 9; ++tap) {
      const int dy = tap / 3, dx = tap % 3;
      bf16x8 av0 = *(const bf16x8*)(ldsA + tap * 1024 + laneN * 32 + aswz);
      bf16x8 av1 = *(const bf16x8*)(ldsA + tap * 1024 + 512 + laneN * 32 + aswz);
      #pragma unroll
      for (int i = 0; i < 4; ++i) {
        if (act[i]) {
          bf16x8 bv = *(const bf16x8*)(ldsB + badd[i][dx] + dy * 1024);
          acc[0][i] = __builtin_amdgcn_mfma_f32_16x16x32_bf16(av0, bv, acc[0][i], 0, 0, 0);
          acc[1][i] = __builtin_amdgcn_mfma_f32_16x16x32_bf16(av1, bv, acc[1][i], 0, 0, 0);
        }
      }
    }
    __syncthreads();   // all waves done reading before next overwrite
  }

  // epilogue: +b1, SiLU, dot w2 over this block's 32 co, reduce kg via shfl
  float b1v[2][4], w2v[2][4];
  #pragma unroll
  for (int m = 0; m < 2; ++m)
    #pragma unroll
    for (int r = 0; r < 4; ++r) {
      int co = cq * 32 + m * 16 + kg * 4 + r;
      b1v[m][r] = b1[co];
      w2v[m][r] = w2[co];
    }
  #pragma unroll
  for (int i = 0; i < 4; ++i) {
    if (!act[i]) continue;
    float part = 0.f;
    #pragma unroll
    for (int m = 0; m < 2; ++m)
      #pragma unroll
      for (int r = 0; r < 4; ++r) {
        float h = acc[m][i][r] + b1v[m][r];
        part = fmaf(w2v[m][r], h * sigmoidf_(h), part);
      }
    part += __shfl_xor(part, 16);
    part += __shfl_xor(part, 32);
    int p = (wv * 4 + i) * 16 + laneN;
    if (kg == 0 && p < 196)
      ws_logit4[((size_t)box * 4 + cq) * 784 + q * 196 + p] = part;
  }
}

// ---------------- Kernel D: sigmoid + paste + binarize (f32 out) ------------
// grid: box(128) x row-group(16 x 32 rows) = 2048 blocks.
__global__ __launch_bounds__(256) void k_paste(
    const float* __restrict__ ws_logit4, const int* __restrict__ ws_keep,
    const int* __restrict__ ws_boxint, const float* __restrict__ b2,
    float* __restrict__ out)
{
  const int box = blockIdx.x >> 4;
  const int yo  = blockIdx.x & 15;
  const int t = threadIdx.x;
  float* mb = out + OFF_MASKS + (size_t)box * 262144 + (size_t)yo * 32 * 512;

  if (!ws_keep[box]) {
    f32x4 z = {0.f, 0.f, 0.f, 0.f};
    f32x4* p = (f32x4*)mb;
    for (int e = t; e < 4096; e += 256)
      __builtin_nontemporal_store(z, p + e);
    return;
  }

  __shared__ float soft[784];
  __shared__ int iys[32];
  __shared__ int bi[4];
  if (t < 4) bi[t] = ws_boxint[box * 4 + t];
  __syncthreads();
  const int x0 = bi[0], y0 = bi[1], x1 = bi[2], y1 = bi[3];
  const int w = x1 - x0 + 1, h = y1 - y0 + 1;
  const float b2v = b2[0];
  const float* l0 = ws_logit4 + (size_t)box * 4 * 784;

  for (int e = t; e < 784; e += 256)
    soft[e] = sigmoidf_(l0[e] + l0[784 + e] + l0[1568 + e] + l0[2352 + e] + b2v);
  if (t < 32) {
    int Y = yo * 32 + t;
    int vy = (Y - y0) * MS;
    int iy = (vy >= 0) ? (vy / h) : 0;
    iys[t] = min(max(iy, 0), MS - 1);
  }
  __syncthreads();

  const int c4 = (t & 127) * 4;   // 4 columns per thread
  const int rr = t >> 7;          // row interleave 0/1
  int ixr[4];
  bool inx[4];
  #pragma unroll
  for (int u = 0; u < 4; ++u) {
    int X = c4 + u;
    int vx = (X - x0) * MS;
    int ix = (vx >= 0) ? (vx / w) : 0;
    ixr[u] = min(max(ix, 0), MS - 1);
    inx[u] = (X >= x0) && (X <= x1);
  }

  int prev_iy = -1;
  f32x4 v = {0.f, 0.f, 0.f, 0.f};
  #pragma unroll 1
  for (int it = 0; it < 16; ++it) {
    int Yl = it * 2 + rr;
    int Y = yo * 32 + Yl;
    f32x4 o;
    if (Y >= y0 && Y <= y1) {
      int iy = iys[Yl];
      if (iy != prev_iy) {
        prev_iy = iy;
        #pragma unroll
        for (int u = 0; u < 4; ++u)
          v[u] = (inx[u] && soft[iy * MS + ixr[u]] > 0.5f) ? 1.f : 0.f;
      }
      o = v;
    } else {
      o = (f32x4){0.f, 0.f, 0.f, 0.f};
    }
    __builtin_nontemporal_store(o, (f32x4*)(mb + (size_t)Yl * 512 + c4));
  }
}

extern "C" void kernel_launch(void* const* d_in, const int* in_sizes, int n_in,
                              void* d_out, int out_size, void* d_ws, size_t ws_size,
                              hipStream_t stream) {
  const float* p0 = (const float*)d_in[0];
  const float* p1 = (const float*)d_in[1];
  const float* p2 = (const float*)d_in[2];
  const float* p3 = (const float*)d_in[3];
  const float* f0 = (const float*)d_in[4];
  const float* f1 = (const float*)d_in[5];
  const float* f2 = (const float*)d_in[6];
  const float* f3 = (const float*)d_in[7];
  const float* w1 = (const float*)d_in[8];
  const float* b1 = (const float*)d_in[9];
  const float* w2 = (const float*)d_in[10];
  const float* b2 = (const float*)d_in[11];
  float* out = (float*)d_out;

  float* wsf = (float*)d_ws;
  float*          ws_boxes  = wsf;                               // 512 f32
  int*            ws_keep   = (int*)(wsf + 512);                 // 128
  int*            ws_boxint = (int*)(wsf + 640);                 // 512
  float*          ws_logit4 = wsf + 1152;                        // 128*4*784 f32
  unsigned short* ws_wt     = (unsigned short*)(wsf + 402560);   // 4*8*9*1024 bf16
  unsigned short* ws_merged = (unsigned short*)(wsf + 550016);   // 2*128*128*256 bf16
  unsigned short* ws_roi    = (unsigned short*)(wsf + 4744320);  // 128*8*30*1024 bf16
  // total ws use: 20,472,960 f32 = 81.9 MB

  k_prep<<<386, 256, 0, stream>>>(p0, p1, p2, p3, f0, f1, f2, f3, w1,
                                  out, ws_boxes, ws_keep, ws_boxint,
                                  ws_wt, ws_merged);
  k_roistage<<<3840, 256, 0, stream>>>(ws_merged, ws_boxes, ws_keep, ws_roi);
  k_conv<<<2048, 256, 0, stream>>>(ws_roi, ws_wt, b1, w2, ws_keep, ws_logit4);
  k_paste<<<2048, 256, 0, stream>>>(ws_logit4, ws_keep, ws_boxint, b2, out);
}

// Round 13
// 262.473 us; speedup vs baseline: 1.1606x; 1.0738x over previous
//
#include <hip/hip_runtime.h>
#include <hip/hip_bf16.h>
#include <cstdint>

#define NTOPK 64
#define A_TOT 340
#define MS 28

// d_out element offsets (f32)
#define OFF_SCORES 0
#define OFF_BOXES  128
#define OFF_LABELS 640
#define OFF_MASKS  768
#define OFF_KEEP   33555200ull

typedef __attribute__((ext_vector_type(4))) float f32x4;
typedef long fp8x8;   // 8 x e4m3 in one 64-bit reg pair

__device__ __forceinline__ float sigmoidf_(float x) { return 1.f / (1.f + expf(-x)); }
__device__ __forceinline__ float bf2f(unsigned u) {
  return __uint_as_float(u << 16);
}
__device__ __forceinline__ unsigned short f2bf(float f) {
  __hip_bfloat16 h = __float2bfloat16(f);  // RNE
  return *(unsigned short*)&h;
}

// ---- Kernel P: fused prep. blocks 0-1: decode+NMS; 2-129: weight transpose
// ---- (f32 -> fp8 e4m3, swizzle baked); 130-385: merged feature build.
__global__ __launch_bounds__(256) void k_prep(
    const float* __restrict__ p0, const float* __restrict__ p1,
    const float* __restrict__ p2, const float* __restrict__ p3,
    const float* __restrict__ f0, const float* __restrict__ f1,
    const float* __restrict__ f2, const float* __restrict__ f3,
    const float* __restrict__ w1,
    float* __restrict__ out,
    float* __restrict__ ws_boxes, int* __restrict__ ws_keep,
    int* __restrict__ ws_boxint,
    unsigned char* __restrict__ wt, unsigned short* __restrict__ mg)
{
  __shared__ __align__(16) char smem_raw[128 * 260 * 2];
  const int bid = blockIdx.x;
  const int t = threadIdx.x;

  if (bid < 2) {
    // ---------------- decode + stable top-64 + shfl NMS ----------------
    const int b = bid;
    float* sc = (float*)smem_raw;                    // [A_TOT]
    float(*bx)[4] = (float(*)[4])(sc + A_TOT);       // [A_TOT][4]
    float* tk_score = (float*)(bx + A_TOT);          // [64]
    float(*tk_box)[4] = (float(*)[4])(tk_score + 64);

    for (int a = t; a < A_TOT; a += 256) {
      const float* pp; int W, HW, la; float stride;
      if (a < 256)      { pp = p0; W = 16; HW = 256; la = a;       stride = 32.f;  }
      else if (a < 320) { pp = p1; W = 8;  HW = 64;  la = a - 256; stride = 64.f;  }
      else if (a < 336) { pp = p2; W = 4;  HW = 16;  la = a - 320; stride = 128.f; }
      else              { pp = p3; W = 2;  HW = 4;   la = a - 336; stride = 256.f; }
      const float* base = pp + (size_t)b * 6 * HW + la;
      float v0 = base[0], v1 = base[HW], v2 = base[2 * HW], v3 = base[3 * HW], v4 = base[4 * HW];
      int gx = la % W, gy = la / W;
      float cx = (v0 + (float)gx) * stride;
      float cy = (v1 + (float)gy) * stride;
      float w_ = expf(v2) * stride;
      float h_ = expf(v3) * stride;
      float score = sigmoidf_(v4);
      sc[a] = (score > 0.5f) ? score : 0.f;
      bx[a][0] = cx - 0.5f * w_;
      bx[a][1] = cy - 0.5f * h_;
      bx[a][2] = cx + 0.5f * w_;
      bx[a][3] = cy + 0.5f * h_;
    }
    __syncthreads();

    // stable top-k by rank counting (ties -> lower index, like lax.top_k)
    for (int a = t; a < A_TOT; a += 256) {
      float my = sc[a];
      int rank = 0;
      for (int j = 0; j < A_TOT; ++j) {
        float o = sc[j];
        rank += (o > my) || (o == my && j < a);
      }
      if (rank < NTOPK) {
        tk_score[rank] = my;
        tk_box[rank][0] = bx[a][0];
        tk_box[rank][1] = bx[a][1];
        tk_box[rank][2] = bx[a][2];
        tk_box[rank][3] = bx[a][3];
      }
    }
    __syncthreads();

    // wave-synchronous sequential NMS on wave 0
    if (t < NTOPK) {
      float x0 = tk_box[t][0], y0 = tk_box[t][1];
      float x1 = tk_box[t][2], y1 = tk_box[t][3];
      float s = tk_score[t];
      float area = fmaxf(x1 - x0, 0.f) * fmaxf(y1 - y0, 0.f);
      int keep = (s > 0.5f) ? 1 : 0;
      for (int i = 0; i < NTOPK - 1; ++i) {
        int   ki = __shfl(keep, i);
        float a0 = __shfl(x0, i);
        float c0 = __shfl(y0, i);
        float a1 = __shfl(x1, i);
        float c1 = __shfl(y1, i);
        float ai = __shfl(area, i);
        if (ki && t > i && keep) {
          float ix0 = fmaxf(a0, x0), iy0 = fmaxf(c0, y0);
          float ix1 = fminf(a1, x1), iy1 = fminf(c1, y1);
          float inter = fmaxf(ix1 - ix0, 0.f) * fmaxf(iy1 - iy0, 0.f);
          float uni = ai + area - inter;
          float iou = inter / fmaxf(uni, 1e-9f);
          if (iou > 0.5f) keep = 0;
        }
      }
      int box = b * NTOPK + t;
      out[OFF_SCORES + box] = keep ? s : 0.f;
      float bv[4] = {x0, y0, x1, y1};
      #pragma unroll
      for (int c = 0; c < 4; ++c) {
        out[OFF_BOXES + box * 4 + c] = bv[c];
        ws_boxes[box * 4 + c] = bv[c];
        float bc = fminf(fmaxf(bv[c], 0.f), 511.f);
        ws_boxint[box * 4 + c] = (int)bc;
      }
      out[OFF_LABELS + box] = 0.f;
      out[OFF_KEEP + box] = keep ? 1.f : 0.f;
      ws_keep[box] = keep;
    }
    return;
  }

  if (bid < 130) {
    // -- w1 f32 [co][ci][3][3] -> wt fp8 [cq][chunk][tap][co32][ci32] with
    // -- octet swizzle baked in: octet slot = (cil>>3) ^ ((col>>2)&3).
    const int co = bid - 2;
    const int ci = t;            // 0..255
    const int c = ci >> 5, cil = ci & 31;
    const int cq = co >> 5, col = co & 31;
    const int slot = ((cil >> 3) ^ ((col >> 2) & 3)) * 8 + (cil & 7);
    const float* src = w1 + ((size_t)co * 256 + ci) * 9;
    #pragma unroll
    for (int tap = 0; tap < 9; ++tap) {
      unsigned u = __builtin_amdgcn_cvt_pk_fp8_f32(src[tap], 0.f, 0, false);
      wt[(((size_t)(cq * 8 + c) * 9 + tap)) * 1024 + col * 32 + slot] =
          (unsigned char)(u & 0xff);
    }
    return;
  }

  // -------- merged[b][y][x][c] bf16 build --------
  {
    const int idx = bid - 130;
    const int b = idx >> 7;
    const int y = idx & 127;
    unsigned short* tile = (unsigned short*)smem_raw;   // [128*260]
    const int x = t & 127, ch = t >> 7;

    {
      const float* src = f0 + ((size_t)b * 64) * 16384 + y * 128 + x;
      for (int cc = 0; cc < 32; ++cc) {
        int cl = ch * 32 + cc;
        tile[x * 260 + cl] = f2bf(src[(size_t)cl * 16384]);
      }
    }
    {
      const float* src = f1 + ((size_t)b * 64) * 4096 + (y >> 1) * 64 + (x >> 1);
      for (int cc = 0; cc < 32; ++cc) {
        int cl = ch * 32 + cc;
        tile[x * 260 + 64 + cl] = f2bf(src[(size_t)cl * 4096]);
      }
    }
    {
      const float* src = f2 + ((size_t)b * 64) * 1024 + (y >> 2) * 32 + (x >> 2);
      for (int cc = 0; cc < 32; ++cc) {
        int cl = ch * 32 + cc;
        tile[x * 260 + 128 + cl] = f2bf(src[(size_t)cl * 1024]);
      }
    }
    {
      const float* src = f3 + ((size_t)b * 64) * 256 + (y >> 3) * 16 + (x >> 3);
      for (int cc = 0; cc < 32; ++cc) {
        int cl = ch * 32 + cc;
        tile[x * 260 + 192 + cl] = f2bf(src[(size_t)cl * 256]);
      }
    }
    __syncthreads();
    unsigned short* dst = mg + (((size_t)b * 128 + y) * 128) * 256;
    for (int it = 0; it < 32; ++it) {
      int qq = t + it * 256;
      int xx = qq >> 6, cg = qq & 63;
      *(ushort4*)(dst + xx * 256 + cg * 4) = *(ushort4*)&tile[xx * 260 + cg * 4];
    }
  }
}

// ------- Kernel S: ROI tiles, bilinear from merged, output fp8 e4m3 ---------
// roi fp8 [box][c 0..7][r 0..29][cell 0..31][ci32], octet swizzle baked:
// octet slot = quad ^ ((cell>>2)&3). XCD swizzle: bid%8 == box%8.
__global__ __launch_bounds__(256) void k_roistage(
    const unsigned short* __restrict__ mg,
    const float* __restrict__ ws_boxes, const int* __restrict__ ws_keep,
    unsigned char* __restrict__ roi)
{
  const int boxLo = blockIdx.x & 7;
  const int r2 = blockIdx.x >> 3;
  const int r = r2 % 30;
  const int box = ((r2 / 30) << 3) | boxLo;
  if (!ws_keep[box]) return;
  const int t = threadIdx.x;
  unsigned char* rbox = roi + (size_t)box * 8 * 30 * 1024;
  const int gr = r - 1;

  if (gr < 0 || gr > 27) {
    uint2 z = {0u, 0u};
    for (int e = t; e < 1024; e += 256) {
      int chunk = e >> 7, rem = e & 127;
      int cell = rem >> 2, quad = rem & 3;
      size_t off = ((size_t)(chunk * 30 + r)) * 1024 + cell * 32 +
                   (quad ^ ((cell >> 2) & 3)) * 8;
      *(uint2*)(rbox + off) = z;
    }
    return;
  }

  __shared__ int   xa_s[MS], xb_s[MS];
  __shared__ float fx_s[MS];
  __shared__ float by_s[4];
  if (t < 4) by_s[t] = ws_boxes[box * 4 + t];
  __syncthreads();
  const float b0 = by_s[0] * 0.25f, b1_ = by_s[1] * 0.25f;
  const float b2_ = by_s[2] * 0.25f, b3_ = by_s[3] * 0.25f;
  if (t < MS) {
    float bw = (b2_ - b0) * (1.f / MS);
    float x = b0 + ((float)t + 0.5f) * bw;
    x = fminf(fmaxf(x, 0.f), 127.f);
    int x0 = (int)floorf(x);
    xa_s[t] = x0; xb_s[t] = min(x0 + 1, 127); fx_s[t] = x - (float)x0;
  }
  float bh = (b3_ - b1_) * (1.f / MS);
  float yy = b1_ + ((float)gr + 0.5f) * bh;
  yy = fminf(fmaxf(yy, 0.f), 127.f);
  int ya = (int)floorf(yy);
  int yb = min(ya + 1, 127);
  float fy = yy - (float)ya;
  __syncthreads();

  const int b = box >> 6;
  const unsigned short* mgb = mg + ((size_t)b * 128 * 128) * 256;

  // e -> chunk = e>>7, cell = (e&127)>>2, quad = e&3; U (ci octet) = chunk*4+quad
  for (int e = t; e < 1024; e += 256) {
    int chunk = e >> 7, rem = e & 127;
    int cell = rem >> 2, quad = rem & 3;
    size_t off = ((size_t)(chunk * 30 + r)) * 1024 + cell * 32 +
                 (quad ^ ((cell >> 2) & 3)) * 8;
    int gc = cell - 1;
    if (gc < 0 || gc > 27) {
      uint2 z = {0u, 0u};
      *(uint2*)(rbox + off) = z;
      continue;
    }
    int U = chunk * 4 + quad;
    int xa = xa_s[gc], xb = xb_s[gc];
    float fx = fx_s[gc];
    float w00 = (1.f - fy) * (1.f - fx), w01 = (1.f - fy) * fx;
    float w10 = fy * (1.f - fx),         w11 = fy * fx;
    uint4 A = *(const uint4*)(mgb + ((size_t)(ya * 128 + xa)) * 256 + U * 8);
    uint4 B = *(const uint4*)(mgb + ((size_t)(ya * 128 + xb)) * 256 + U * 8);
    uint4 C = *(const uint4*)(mgb + ((size_t)(yb * 128 + xa)) * 256 + U * 8);
    uint4 D = *(const uint4*)(mgb + ((size_t)(yb * 128 + xb)) * 256 + U * 8);
    const unsigned* pa = (const unsigned*)&A;
    const unsigned* pb = (const unsigned*)&B;
    const unsigned* pc = (const unsigned*)&C;
    const unsigned* pd = (const unsigned*)&D;
    float f[8];
    #pragma unroll
    for (int k2 = 0; k2 < 4; ++k2) {
      f[2 * k2] = bf2f(pa[k2] & 0xffffu) * w00 + bf2f(pb[k2] & 0xffffu) * w01 +
                  bf2f(pc[k2] & 0xffffu) * w10 + bf2f(pd[k2] & 0xffffu) * w11;
      f[2 * k2 + 1] = bf2f(pa[k2] >> 16) * w00 + bf2f(pb[k2] >> 16) * w01 +
                      bf2f(pc[k2] >> 16) * w10 + bf2f(pd[k2] >> 16) * w11;
    }
    unsigned o0 = __builtin_amdgcn_cvt_pk_fp8_f32(f[0], f[1], 0, false);
    o0 = __builtin_amdgcn_cvt_pk_fp8_f32(f[2], f[3], o0, true);
    unsigned o1 = __builtin_amdgcn_cvt_pk_fp8_f32(f[4], f[5], 0, false);
    o1 = __builtin_amdgcn_cvt_pk_fp8_f32(f[6], f[7], o1, true);
    uint2 pk; pk.x = o0; pk.y = o1;
    *(uint2*)(rbox + off) = pk;
  }
}

// ------- Kernel G: conv1 3x3 as 9 shifted fp8 MFMA GEMMs + SiLU + conv2 ----
// grid (box, quarter, co-quad) = 2048, XCD swizzle bid%8 == box%8.
// fp8 e4m3 A+B, fp32 accumulate (mfma_f32_16x16x32_fp8_fp8). A and B staged
// in LDS per chunk (9 KB + 9 KB, swizzle pre-baked in global layouts ->
// pure linear copies), register-prefetched, 2 barriers/chunk.
__global__ __launch_bounds__(256, 4) void k_conv(
    const unsigned char* __restrict__ roi,  // [box][c][r30][cell32][ci32^swz]
    const unsigned char* __restrict__ wt,   // [cq][c][tap][co32][ci32^swz]
    const float* __restrict__ b1, const float* __restrict__ w2,
    const int* __restrict__ ws_keep,
    float* __restrict__ ws_logit4)          // [128][4][784]
{
  const int bid = blockIdx.x;
  const int boxLo = bid & 7;
  const int r1 = bid >> 3;
  const int cq = r1 & 3;
  const int q = (r1 >> 2) & 3;
  const int box = ((r1 >> 4) << 3) | boxLo;
  if (!ws_keep[box]) return;
  const int t = threadIdx.x;
  const int lane = t & 63, wv = t >> 6;
  const int laneN = lane & 15, kg = lane >> 4;

  // bytes 0..9215 = A [tap][co32][ci32^swz]; 9216..18431 = B [r9][cell32][ci32^swz]
  __shared__ __align__(16) unsigned char lds[18432];

  // per-(i,dx) swizzled B byte offsets; act[i]: tile contains real pixels
  int badd[4][3];
  bool act[4];
  #pragma unroll
  for (int i = 0; i < 4; ++i) {
    int tile = wv * 4 + i;
    act[i] = (tile * 16) < 196;
    int p = tile * 16 + laneN;
    if (p > 195) p = 195;
    int py = p / 28, px = p - py * 28;
    #pragma unroll
    for (int dx = 0; dx < 3; ++dx) {
      int cell = px + dx;
      badd[i][dx] = 9216 + py * 1024 + cell * 32 + (kg ^ ((cell >> 2) & 3)) * 8;
    }
  }
  // A octet swizzle: same xor term for co=laneN and co=16+laneN
  const int aswz = (kg ^ ((laneN >> 2) & 3)) * 8;

  f32x4 acc[2][4];
  #pragma unroll
  for (int m = 0; m < 2; ++m)
    #pragma unroll
    for (int i = 0; i < 4; ++i) acc[m][i] = (f32x4){0.f, 0.f, 0.f, 0.f};

  const uint4* rbase = (const uint4*)roi;
  const uint4* wbase = (const uint4*)wt;

  uint4 ga0, ga1, ga2;   // A staging regs (576 uint4 / block)
  uint4 gb0, gb1, gb2;   // B staging regs (576 uint4 / block)
  auto issue_load = [&](int c) {
    const uint4* wa = wbase + (size_t)(cq * 8 + c) * 576;
    ga0 = wa[t]; ga1 = wa[t + 256];
    if (t < 64) ga2 = wa[t + 512];
    const uint4* s = rbase + ((size_t)(box * 8 + c) * 30 + q * 7) * 64;
    gb0 = s[t]; gb1 = s[t + 256];
    if (t < 64) gb2 = s[t + 512];
  };

  issue_load(0);
  #pragma unroll 1
  for (int c = 0; c < 8; ++c) {
    {
      uint4* da = (uint4*)lds;
      da[t] = ga0; da[t + 256] = ga1;
      if (t < 64) da[t + 512] = ga2;
      uint4* db = (uint4*)(lds + 9216);
      db[t] = gb0; db[t + 256] = gb1;
      if (t < 64) db[t + 512] = gb2;
    }
    __syncthreads();
    if (c < 7) issue_load(c + 1);   // in flight across compute
    #pragma unroll
    for (int tap = 0; tap < 9; ++tap) {
      const int dy = tap / 3, dx = tap % 3;
      fp8x8 av0 = *(const fp8x8*)(lds + tap * 1024 + laneN * 32 + aswz);
      fp8x8 av1 = *(const fp8x8*)(lds + tap * 1024 + 512 + laneN * 32 + aswz);
      #pragma unroll
      for (int i = 0; i < 4; ++i) {
        if (act[i]) {
          fp8x8 bv = *(const fp8x8*)(lds + badd[i][dx] + dy * 1024);
          acc[0][i] = __builtin_amdgcn_mfma_f32_16x16x32_fp8_fp8(av0, bv, acc[0][i], 0, 0, 0);
          acc[1][i] = __builtin_amdgcn_mfma_f32_16x16x32_fp8_fp8(av1, bv, acc[1][i], 0, 0, 0);
        }
      }
    }
    __syncthreads();   // all waves done reading before next overwrite
  }

  // epilogue: +b1, SiLU, dot w2 over this block's 32 co, reduce kg via shfl
  float b1v[2][4], w2v[2][4];
  #pragma unroll
  for (int m = 0; m < 2; ++m)
    #pragma unroll
    for (int r = 0; r < 4; ++r) {
      int co = cq * 32 + m * 16 + kg * 4 + r;
      b1v[m][r] = b1[co];
      w2v[m][r] = w2[co];
    }
  #pragma unroll
  for (int i = 0; i < 4; ++i) {
    if (!act[i]) continue;
    float part = 0.f;
    #pragma unroll
    for (int m = 0; m < 2; ++m)
      #pragma unroll
      for (int r = 0; r < 4; ++r) {
        float h = acc[m][i][r] + b1v[m][r];
        part = fmaf(w2v[m][r], h * sigmoidf_(h), part);
      }
    part += __shfl_xor(part, 16);
    part += __shfl_xor(part, 32);
    int p = (wv * 4 + i) * 16 + laneN;
    if (kg == 0 && p < 196)
      ws_logit4[((size_t)box * 4 + cq) * 784 + q * 196 + p] = part;
  }
}

// ---------------- Kernel D: sigmoid + paste + binarize (f32 out) ------------
// grid: box(128) x row-group(16 x 32 rows) = 2048 blocks.
__global__ __launch_bounds__(256) void k_paste(
    const float* __restrict__ ws_logit4, const int* __restrict__ ws_keep,
    const int* __restrict__ ws_boxint, const float* __restrict__ b2,
    float* __restrict__ out)
{
  const int box = blockIdx.x >> 4;
  const int yo  = blockIdx.x & 15;
  const int t = threadIdx.x;
  float* mb = out + OFF_MASKS + (size_t)box * 262144 + (size_t)yo * 32 * 512;

  if (!ws_keep[box]) {
    f32x4 z = {0.f, 0.f, 0.f, 0.f};
    f32x4* p = (f32x4*)mb;
    for (int e = t; e < 4096; e += 256)
      __builtin_nontemporal_store(z, p + e);
    return;
  }

  __shared__ float soft[784];
  __shared__ int iys[32];
  __shared__ int bi[4];
  if (t < 4) bi[t] = ws_boxint[box * 4 + t];
  __syncthreads();
  const int x0 = bi[0], y0 = bi[1], x1 = bi[2], y1 = bi[3];
  const int w = x1 - x0 + 1, h = y1 - y0 + 1;
  const float b2v = b2[0];
  const float* l0 = ws_logit4 + (size_t)box * 4 * 784;

  for (int e = t; e < 784; e += 256)
    soft[e] = sigmoidf_(l0[e] + l0[784 + e] + l0[1568 + e] + l0[2352 + e] + b2v);
  if (t < 32) {
    int Y = yo * 32 + t;
    int vy = (Y - y0) * MS;
    int iy = (vy >= 0) ? (vy / h) : 0;
    iys[t] = min(max(iy, 0), MS - 1);
  }
  __syncthreads();

  const int c4 = (t & 127) * 4;   // 4 columns per thread
  const int rr = t >> 7;          // row interleave 0/1
  int ixr[4];
  bool inx[4];
  #pragma unroll
  for (int u = 0; u < 4; ++u) {
    int X = c4 + u;
    int vx = (X - x0) * MS;
    int ix = (vx >= 0) ? (vx / w) : 0;
    ixr[u] = min(max(ix, 0), MS - 1);
    inx[u] = (X >= x0) && (X <= x1);
  }

  int prev_iy = -1;
  f32x4 v = {0.f, 0.f, 0.f, 0.f};
  #pragma unroll 1
  for (int it = 0; it < 16; ++it) {
    int Yl = it * 2 + rr;
    int Y = yo * 32 + Yl;
    f32x4 o;
    if (Y >= y0 && Y <= y1) {
      int iy = iys[Yl];
      if (iy != prev_iy) {
        prev_iy = iy;
        #pragma unroll
        for (int u = 0; u < 4; ++u)
          v[u] = (inx[u] && soft[iy * MS + ixr[u]] > 0.5f) ? 1.f : 0.f;
      }
      o = v;
    } else {
      o = (f32x4){0.f, 0.f, 0.f, 0.f};
    }
    __builtin_nontemporal_store(o, (f32x4*)(mb + (size_t)Yl * 512 + c4));
  }
}

extern "C" void kernel_launch(void* const* d_in, const int* in_sizes, int n_in,
                              void* d_out, int out_size, void* d_ws, size_t ws_size,
                              hipStream_t stream) {
  const float* p0 = (const float*)d_in[0];
  const float* p1 = (const float*)d_in[1];
  const float* p2 = (const float*)d_in[2];
  const float* p3 = (const float*)d_in[3];
  const float* f0 = (const float*)d_in[4];
  const float* f1 = (const float*)d_in[5];
  const float* f2 = (const float*)d_in[6];
  const float* f3 = (const float*)d_in[7];
  const float* w1 = (const float*)d_in[8];
  const float* b1 = (const float*)d_in[9];
  const float* w2 = (const float*)d_in[10];
  const float* b2 = (const float*)d_in[11];
  float* out = (float*)d_out;

  float* wsf = (float*)d_ws;
  float*          ws_boxes  = wsf;                                // 512 f32
  int*            ws_keep   = (int*)(wsf + 512);                  // 128
  int*            ws_boxint = (int*)(wsf + 640);                  // 512
  float*          ws_logit4 = wsf + 1152;                         // 128*4*784 f32
  unsigned char*  ws_wt     = (unsigned char*)(wsf + 402560);     // 4*8*9*1024 fp8
  unsigned short* ws_merged = (unsigned short*)(wsf + 476288);    // 2*128*128*256 bf16
  unsigned char*  ws_roi    = (unsigned char*)(wsf + 4670592);    // 128*8*30*1024 fp8
  // total ws use: 12,534,912 f32 = 50.1 MB

  k_prep<<<386, 256, 0, stream>>>(p0, p1, p2, p3, f0, f1, f2, f3, w1,
                                  out, ws_boxes, ws_keep, ws_boxint,
                                  ws_wt, ws_merged);
  k_roistage<<<3840, 256, 0, stream>>>(ws_merged, ws_boxes, ws_keep, ws_roi);
  k_conv<<<2048, 256, 0, stream>>>(ws_roi, ws_wt, b1, w2, ws_keep, ws_logit4);
  k_paste<<<2048, 256, 0, stream>>>(ws_logit4, ws_keep, ws_boxint, b2, out);
}